// Round 1
// baseline (210.996 us; speedup 1.0000x reference)
//
#include <hip/hip_runtime.h>
#include <hip/hip_bf16.h>
#include <math.h>

#define D_DIM 1024
#define NROWS 32768      // 4*16*512
#define NE_ROWS 1024     // 4*16*16 unique engram rows
#define A1_ROWS 1536     // engram rows + 512 pos rows

typedef __attribute__((ext_vector_type(8))) short bf16x8;
typedef __attribute__((ext_vector_type(4))) float f32x4;

static __device__ __forceinline__ ushort f2bf(float f) {
  union { float f; unsigned u; } un; un.f = f;
  unsigned u = un.u;
  unsigned r = u + 0x7fffu + ((u >> 16) & 1u);
  return (ushort)(r >> 16);
}

// ---- cast fp32 -> bf16, vectorized x4 ----
__global__ void cast_kernel(const float* __restrict__ src, ushort* __restrict__ dst, int n4) {
  int i = blockIdx.x * blockDim.x + threadIdx.x;
  if (i >= n4) return;
  float4 v = ((const float4*)src)[i];
  ushort4 o;
  o.x = f2bf(v.x); o.y = f2bf(v.y); o.z = f2bf(v.z); o.w = f2bf(v.w);
  ((ushort4*)dst)[i] = o;
}

// ---- bf16 MFMA GEMM: C(MxN) = A(MxK) * B(NxK)^T, all row-major, fp32 out ----
// 128x128 tile, BK=64, 4 waves (2x2 of 64x64), 16x16x32 MFMA, global_load_lds w=16.
__global__ __launch_bounds__(256) void gemm_bt(const ushort* __restrict__ A,
                                               const ushort* __restrict__ B,
                                               float* __restrict__ C,
                                               int M, int N, int K) {
  __shared__ ushort sA[128 * 64];
  __shared__ ushort sB[128 * 64];

  int nwg = gridDim.x;
  int bid = blockIdx.x;
  if ((nwg & 7) == 0) {              // XCD-aware swizzle (bijective when nwg%8==0)
    int cpx = nwg >> 3;
    bid = (bid & 7) * cpx + (bid >> 3);
  }
  int ntn = N >> 7;
  int mt = bid / ntn, nt = bid % ntn;
  int brow = mt << 7, bcol = nt << 7;

  int tid = threadIdx.x;
  int wv = tid >> 6, lane = tid & 63;
  int wm = (wv >> 1) << 6, wn = (wv & 1) << 6;   // wave's 64x64 quadrant
  int lr = lane & 15, lk = lane >> 4;            // fragment row / k-group
  int srow = lane >> 3, scol = (lane & 7) << 3;  // staging row/col within chunk

  f32x4 acc[4][4];
#pragma unroll
  for (int m = 0; m < 4; ++m)
#pragma unroll
    for (int n = 0; n < 4; ++n) acc[m][n] = (f32x4){0.f, 0.f, 0.f, 0.f};

  for (int k0 = 0; k0 < K; k0 += 64) {
    __syncthreads();   // previous iter's LDS reads done before restaging
#pragma unroll
    for (int j = 0; j < 4; ++j) {
      int c = (wv << 2) + j;           // chunk 0..15, 8 rows each
      int row = (c << 3) + srow;
      const ushort* gA = A + (brow + row) * K + k0 + scol;
      const ushort* gB = B + (bcol + row) * K + k0 + scol;
      __builtin_amdgcn_global_load_lds(
          (const __attribute__((address_space(1))) unsigned int*)gA,
          (__attribute__((address_space(3))) unsigned int*)&sA[c << 9], 16, 0, 0);
      __builtin_amdgcn_global_load_lds(
          (const __attribute__((address_space(1))) unsigned int*)gB,
          (__attribute__((address_space(3))) unsigned int*)&sB[c << 9], 16, 0, 0);
    }
    __syncthreads();   // staging visible (compiler drains vmcnt before barrier)
#pragma unroll
    for (int kk = 0; kk < 2; ++kk) {
      bf16x8 af[4], bfr[4];
#pragma unroll
      for (int m = 0; m < 4; ++m)
        af[m] = *(const bf16x8*)&sA[(wm + (m << 4) + lr) * 64 + (kk << 5) + (lk << 3)];
#pragma unroll
      for (int n = 0; n < 4; ++n)
        bfr[n] = *(const bf16x8*)&sB[(wn + (n << 4) + lr) * 64 + (kk << 5) + (lk << 3)];
#pragma unroll
      for (int m = 0; m < 4; ++m)
#pragma unroll
        for (int n = 0; n < 4; ++n)
          acc[m][n] = __builtin_amdgcn_mfma_f32_16x16x32_bf16(af[m], bfr[n], acc[m][n], 0, 0, 0);
    }
  }

  // C/D layout: col = lane&15, row = (lane>>4)*4 + i   [m89-verified]
#pragma unroll
  for (int m = 0; m < 4; ++m)
#pragma unroll
    for (int n = 0; n < 4; ++n)
#pragma unroll
      for (int i = 0; i < 4; ++i) {
        int row = brow + wm + (m << 4) + (lk << 2) + i;
        int col = bcol + wn + (n << 4) + lr;
        C[(long)row * N + col] = acc[m][n][i];
      }
}

// ---- h = gelu_exact(xw1_e[er] + xw1_p[w] + b1) -> bf16; one block per row ----
__global__ __launch_bounds__(256) void gelu_kernel(const float* __restrict__ xw1,
                                                   const float* __restrict__ b1,
                                                   ushort* __restrict__ h) {
  int r = blockIdx.x;     // 0..32767
  int t = threadIdx.x;    // 0..255, 4 elems each
  int bn = r >> 9;
  int w = r & 511;
  int er = bn * 16 + (w >> 5);
  float4 e = ((const float4*)(xw1 + er * D_DIM))[t];
  float4 p = ((const float4*)(xw1 + (NE_ROWS + w) * D_DIM))[t];
  float4 b = ((const float4*)b1)[t];
  float v[4] = {e.x + p.x + b.x, e.y + p.y + b.y, e.z + p.z + b.z, e.w + p.w + b.w};
  ushort4 o;
  float g0 = 0.5f * v[0] * (1.0f + erff(v[0] * 0.70710678118654752f));
  float g1 = 0.5f * v[1] * (1.0f + erff(v[1] * 0.70710678118654752f));
  float g2 = 0.5f * v[2] * (1.0f + erff(v[2] * 0.70710678118654752f));
  float g3 = 0.5f * v[3] * (1.0f + erff(v[3] * 0.70710678118654752f));
  o.x = f2bf(g0); o.y = f2bf(g1); o.z = f2bf(g2); o.w = f2bf(g3);
  ((ushort4*)(h + (long)r * D_DIM))[t] = o;
}

// ---- out = LayerNorm((engram+pos) + y + b2); y read in-place from out ----
__global__ __launch_bounds__(256) void ln_kernel(const float* __restrict__ eng,
                                                 const float* __restrict__ pos,
                                                 const float* __restrict__ b2,
                                                 const float* __restrict__ gamma,
                                                 const float* __restrict__ beta,
                                                 float* __restrict__ out) {
  __shared__ float red[8];
  int r = blockIdx.x;
  int t = threadIdx.x;
  int bn = r >> 9, w = r & 511;
  int er = bn * 16 + (w >> 5);
  float4 xe = ((const float4*)(eng + er * D_DIM))[t];
  float4 xp = ((const float4*)(pos + w * D_DIM))[t];
  float4 y  = ((const float4*)(out + (long)r * D_DIM))[t];
  float4 bb = ((const float4*)b2)[t];
  float v0 = xe.x + xp.x + y.x + bb.x;
  float v1 = xe.y + xp.y + y.y + bb.y;
  float v2 = xe.z + xp.z + y.z + bb.z;
  float v3 = xe.w + xp.w + y.w + bb.w;
  float s  = v0 + v1 + v2 + v3;
  float sq = v0 * v0 + v1 * v1 + v2 * v2 + v3 * v3;
  int lane = t & 63, wv = t >> 6;
#pragma unroll
  for (int off = 32; off > 0; off >>= 1) {
    s  += __shfl_down(s, off);
    sq += __shfl_down(sq, off);
  }
  if (lane == 0) { red[wv] = s; red[4 + wv] = sq; }
  __syncthreads();
  float S  = red[0] + red[1] + red[2] + red[3];
  float SQ = red[4] + red[5] + red[6] + red[7];
  float mu = S * (1.0f / 1024.0f);
  float var = SQ * (1.0f / 1024.0f) - mu * mu;
  float rs = rsqrtf(var + 1e-5f);
  float4 g = ((const float4*)gamma)[t];
  float4 bt = ((const float4*)beta)[t];
  float4 o;
  o.x = (v0 - mu) * rs * g.x + bt.x;
  o.y = (v1 - mu) * rs * g.y + bt.y;
  o.z = (v2 - mu) * rs * g.z + bt.z;
  o.w = (v3 - mu) * rs * g.w + bt.w;
  ((float4*)(out + (long)r * D_DIM))[t] = o;
}

extern "C" void kernel_launch(void* const* d_in, const int* in_sizes, int n_in,
                              void* d_out, int out_size, void* d_ws, size_t ws_size,
                              hipStream_t stream) {
  const float* eng   = (const float*)d_in[0];
  const float* pos   = (const float*)d_in[1];
  const float* w1    = (const float*)d_in[2];
  const float* b1    = (const float*)d_in[3];
  const float* w2    = (const float*)d_in[4];
  const float* b2    = (const float*)d_in[5];
  const float* gamma = (const float*)d_in[6];
  const float* beta  = (const float*)d_in[7];
  float* out = (float*)d_out;

  char* ws = (char*)d_ws;
  ushort* w1b = (ushort*)(ws);                     // 2 MiB
  ushort* w2b = (ushort*)(ws + (2u << 20));        // 2 MiB
  ushort* a1b = (ushort*)(ws + (4u << 20));        // 3 MiB: 1536x1024 bf16
  float*  xw1 = (float*)(ws + (7u << 20));         // 6 MiB: 1536x1024 f32
  ushort* hb  = (ushort*)(ws + (13u << 20));       // 64 MiB: 32768x1024 bf16

  // 1) casts to bf16
  cast_kernel<<<1024, 256, 0, stream>>>(w1, w1b, 1024 * 1024 / 4);
  cast_kernel<<<1024, 256, 0, stream>>>(w2, w2b, 1024 * 1024 / 4);
  cast_kernel<<<1024, 256, 0, stream>>>(eng, a1b, 1024 * 1024 / 4);
  cast_kernel<<<512, 256, 0, stream>>>(pos, a1b + 1024 * 1024, 512 * 1024 / 4);

  // 2) GEMM1: xw1 = [engrams; pos] @ W1^T   (1536 x 1024 x 1024)
  gemm_bt<<<(A1_ROWS / 128) * (D_DIM / 128), 256, 0, stream>>>(a1b, w1b, xw1,
                                                               A1_ROWS, D_DIM, D_DIM);

  // 3) h = gelu(xw1_e + xw1_p + b1) -> bf16
  gelu_kernel<<<NROWS, 256, 0, stream>>>(xw1, b1, hb);

  // 4) GEMM2: y = h @ W2^T -> fp32 into d_out   (32768 x 1024 x 1024)
  gemm_bt<<<(NROWS / 128) * (D_DIM / 128), 256, 0, stream>>>(hb, w2b, out,
                                                             NROWS, D_DIM, D_DIM);

  // 5) LayerNorm epilogue (exact fp32 residual recompute), in-place on d_out
  ln_kernel<<<NROWS, 256, 0, stream>>>(eng, pos, b2, gamma, beta, out);
}

// Round 2
// 201.366 us; speedup vs baseline: 1.0478x; 1.0478x over previous
//
#include <hip/hip_runtime.h>
#include <hip/hip_bf16.h>
#include <math.h>

#define D_DIM 1024
#define NROWS 32768      // 4*16*512
#define NE_ROWS 1024     // 4*16*16 unique engram rows
#define A1_ROWS 1536     // engram rows + 512 pos rows

typedef __attribute__((ext_vector_type(8))) short bf16x8;
typedef __attribute__((ext_vector_type(4))) float f32x4;

static __device__ __forceinline__ ushort f2bf(float f) {
  union { float f; unsigned u; } un; un.f = f;
  unsigned u = un.u;
  unsigned r = u + 0x7fffu + ((u >> 16) & 1u);
  return (ushort)(r >> 16);
}

// ---- cast fp32 -> bf16, vectorized x4 ----
__global__ void cast_kernel(const float* __restrict__ src, ushort* __restrict__ dst, int n4) {
  int i = blockIdx.x * blockDim.x + threadIdx.x;
  if (i >= n4) return;
  float4 v = ((const float4*)src)[i];
  ushort4 o;
  o.x = f2bf(v.x); o.y = f2bf(v.y); o.z = f2bf(v.z); o.w = f2bf(v.w);
  ((ushort4*)dst)[i] = o;
}

// ---- 128x128 bf16 MFMA GEMM (m97 structure) — used for small GEMM1 ----
__global__ __launch_bounds__(256) void gemm_bt(const ushort* __restrict__ A,
                                               const ushort* __restrict__ B,
                                               float* __restrict__ C,
                                               int M, int N, int K) {
  __shared__ ushort sA[128 * 64];
  __shared__ ushort sB[128 * 64];

  int nwg = gridDim.x;
  int bid = blockIdx.x;
  if ((nwg & 7) == 0) {
    int cpx = nwg >> 3;
    bid = (bid & 7) * cpx + (bid >> 3);
  }
  int ntn = N >> 7;
  int mt = bid / ntn, nt = bid % ntn;
  int brow = mt << 7, bcol = nt << 7;

  int tid = threadIdx.x;
  int wv = tid >> 6, lane = tid & 63;
  int wm = (wv >> 1) << 6, wn = (wv & 1) << 6;
  int lr = lane & 15, lk = lane >> 4;
  int srow = lane >> 3, scol = (lane & 7) << 3;

  f32x4 acc[4][4];
#pragma unroll
  for (int m = 0; m < 4; ++m)
#pragma unroll
    for (int n = 0; n < 4; ++n) acc[m][n] = (f32x4){0.f, 0.f, 0.f, 0.f};

  for (int k0 = 0; k0 < K; k0 += 64) {
    __syncthreads();
#pragma unroll
    for (int j = 0; j < 4; ++j) {
      int c = (wv << 2) + j;
      int row = (c << 3) + srow;
      const ushort* gA = A + (brow + row) * K + k0 + scol;
      const ushort* gB = B + (bcol + row) * K + k0 + scol;
      __builtin_amdgcn_global_load_lds(
          (const __attribute__((address_space(1))) unsigned int*)gA,
          (__attribute__((address_space(3))) unsigned int*)&sA[c << 9], 16, 0, 0);
      __builtin_amdgcn_global_load_lds(
          (const __attribute__((address_space(1))) unsigned int*)gB,
          (__attribute__((address_space(3))) unsigned int*)&sB[c << 9], 16, 0, 0);
    }
    __syncthreads();
#pragma unroll
    for (int kk = 0; kk < 2; ++kk) {
      bf16x8 af[4], bfr[4];
#pragma unroll
      for (int m = 0; m < 4; ++m)
        af[m] = *(const bf16x8*)&sA[(wm + (m << 4) + lr) * 64 + (kk << 5) + (lk << 3)];
#pragma unroll
      for (int n = 0; n < 4; ++n)
        bfr[n] = *(const bf16x8*)&sB[(wn + (n << 4) + lr) * 64 + (kk << 5) + (lk << 3)];
#pragma unroll
      for (int m = 0; m < 4; ++m)
#pragma unroll
        for (int n = 0; n < 4; ++n)
          acc[m][n] = __builtin_amdgcn_mfma_f32_16x16x32_bf16(af[m], bfr[n], acc[m][n], 0, 0, 0);
    }
  }

#pragma unroll
  for (int m = 0; m < 4; ++m)
#pragma unroll
    for (int n = 0; n < 4; ++n)
#pragma unroll
      for (int i = 0; i < 4; ++i) {
        int row = brow + wm + (m << 4) + (lk << 2) + i;
        int col = bcol + wn + (n << 4) + lr;
        C[(long)row * N + col] = acc[m][n][i];
      }
}

// ---- 256x256-tile 8-wave pipelined bf16 GEMM: C = A(MxK) * B(NxK)^T ----
// BK=32, 4 LDS buffers, prefetch depth 3, counted vmcnt, T2 swizzle, T5 setprio.
// Requires M%256==0, N%256==0, K%32==0, K/32>=4, grid%8==0.
__global__ __launch_bounds__(512, 2) void gemm_bt_256(const ushort* __restrict__ A,
                                                      const ushort* __restrict__ B,
                                                      float* __restrict__ C,
                                                      int M, int N, int K) {
  __shared__ ushort sA[4][8192];   // [buf][256 rows x 32 cols]
  __shared__ ushort sB[4][8192];

  int nwg = gridDim.x;
  int bid = blockIdx.x;
  int cpx = nwg >> 3;              // XCD swizzle (nwg%8==0 guaranteed by launch)
  bid = (bid & 7) * cpx + (bid >> 3);
  int ntn = N >> 8;
  int mt = bid / ntn, nt = bid - mt * ntn;
  long brow = (long)mt << 8;
  int bcol = nt << 8;

  int tid = threadIdx.x;
  int wv = tid >> 6, lane = tid & 63;
  int wr = wv >> 2, wc = wv & 3;     // 2x4 wave grid
  int wm = wr << 7, wn = wc << 6;    // wave tile: 128(M) x 64(N)
  int lr = lane & 15, lk = lane >> 4;

  // Staging: thread covers tile-row r=(tid>>2)+j*128, physical 16B slot tid&3.
  // LDS[r][s] holds logical (r, s ^ (r&3))  -> load global slot (tid&3)^(r&3).
  int srow = tid >> 2;
  int sslot = ((tid & 3) ^ (srow & 3)) << 3;   // element offset within row
  const ushort* aSrc = A + (brow + srow) * (long)K + sslot;
  const ushort* bSrc = B + (long)(bcol + srow) * K + sslot;
  int dBase = wv << 9;                          // (wv*64)*8 ushorts, wave-uniform

  // Fragment read offsets (swizzled): logical k-slot lk at row r -> phys lk^(r&3)
  int rdswz = (lk ^ (lr & 3)) << 3;
  int aRead = (wm + lr) * 32 + rdswz;
  int bRead = (wn + lr) * 32 + rdswz;

  f32x4 acc[8][4];
#pragma unroll
  for (int m = 0; m < 8; ++m)
#pragma unroll
    for (int n = 0; n < 4; ++n) acc[m][n] = (f32x4){0.f, 0.f, 0.f, 0.f};

  const int NT = K >> 5;   // # of K-tiles (32 for K=1024)

#define STAGE(kt) do {                                                          \
    int b_ = (kt) & 3; int k0_ = (kt) << 5;                                     \
    _Pragma("unroll")                                                           \
    for (int j = 0; j < 2; ++j) {                                               \
      __builtin_amdgcn_global_load_lds(                                         \
        (const __attribute__((address_space(1))) unsigned int*)(aSrc + k0_ + (long)(j << 7) * K), \
        (__attribute__((address_space(3))) unsigned int*)&sA[b_][dBase + (j << 12)], 16, 0, 0);   \
      __builtin_amdgcn_global_load_lds(                                         \
        (const __attribute__((address_space(1))) unsigned int*)(bSrc + k0_ + (long)(j << 7) * K), \
        (__attribute__((address_space(3))) unsigned int*)&sB[b_][dBase + (j << 12)], 16, 0, 0);   \
    } } while (0)

  // Prologue: fill pipeline with K-tiles 0,1,2 (12 loads/thread outstanding)
  STAGE(0); STAGE(1); STAGE(2);

  for (int t = 0; t < NT; ++t) {
    if (t + 3 < NT) {
      STAGE(t + 3);
      asm volatile("s_waitcnt vmcnt(12)" ::: "memory");  // tile t landed; t+1..t+3 in flight
    } else if (t == NT - 3) {
      asm volatile("s_waitcnt vmcnt(8)" ::: "memory");
    } else if (t == NT - 2) {
      asm volatile("s_waitcnt vmcnt(4)" ::: "memory");
    } else {
      asm volatile("s_waitcnt vmcnt(0)" ::: "memory");
    }
    __builtin_amdgcn_s_barrier();    // all waves see tile t in LDS

    int b = t & 3;
    const ushort* pA = &sA[b][aRead];
    const ushort* pB = &sB[b][bRead];
    bf16x8 bF[4], aF[4];
#pragma unroll
    for (int n = 0; n < 4; ++n) bF[n] = *(const bf16x8*)(pB + n * 512);
#pragma unroll
    for (int m = 0; m < 4; ++m) aF[m] = *(const bf16x8*)(pA + m * 512);
    __builtin_amdgcn_s_setprio(1);
#pragma unroll
    for (int m = 0; m < 4; ++m)
#pragma unroll
      for (int n = 0; n < 4; ++n)
        acc[m][n] = __builtin_amdgcn_mfma_f32_16x16x32_bf16(aF[m], bF[n], acc[m][n], 0, 0, 0);
    __builtin_amdgcn_s_setprio(0);
#pragma unroll
    for (int m = 0; m < 4; ++m) aF[m] = *(const bf16x8*)(pA + (m + 4) * 512);
    __builtin_amdgcn_s_setprio(1);
#pragma unroll
    for (int m = 0; m < 4; ++m)
#pragma unroll
      for (int n = 0; n < 4; ++n)
        acc[m + 4][n] = __builtin_amdgcn_mfma_f32_16x16x32_bf16(aF[m], bF[n], acc[m + 4][n], 0, 0, 0);
    __builtin_amdgcn_s_setprio(0);
    __builtin_amdgcn_s_barrier();    // reads of buf[t&3] done before re-stage
  }
#undef STAGE

  // Epilogue: C/D layout col=lane&15, row=(lane>>4)*4+i
#pragma unroll
  for (int m = 0; m < 8; ++m)
#pragma unroll
    for (int n = 0; n < 4; ++n) {
      long row = brow + wm + (m << 4) + (lk << 2);
      int col = bcol + wn + (n << 4) + lr;
      float* cp = C + row * N + col;
#pragma unroll
      for (int i = 0; i < 4; ++i) cp[(long)i * N] = acc[m][n][i];
    }
}

// ---- h = gelu_exact(xw1_e[er] + xw1_p[w] + b1) -> bf16; one block per row ----
__global__ __launch_bounds__(256) void gelu_kernel(const float* __restrict__ xw1,
                                                   const float* __restrict__ b1,
                                                   ushort* __restrict__ h) {
  int r = blockIdx.x;
  int t = threadIdx.x;
  int bn = r >> 9;
  int w = r & 511;
  int er = bn * 16 + (w >> 5);
  float4 e = ((const float4*)(xw1 + er * D_DIM))[t];
  float4 p = ((const float4*)(xw1 + (NE_ROWS + w) * D_DIM))[t];
  float4 b = ((const float4*)b1)[t];
  float v[4] = {e.x + p.x + b.x, e.y + p.y + b.y, e.z + p.z + b.z, e.w + p.w + b.w};
  ushort4 o;
  float g0 = 0.5f * v[0] * (1.0f + erff(v[0] * 0.70710678118654752f));
  float g1 = 0.5f * v[1] * (1.0f + erff(v[1] * 0.70710678118654752f));
  float g2 = 0.5f * v[2] * (1.0f + erff(v[2] * 0.70710678118654752f));
  float g3 = 0.5f * v[3] * (1.0f + erff(v[3] * 0.70710678118654752f));
  o.x = f2bf(g0); o.y = f2bf(g1); o.z = f2bf(g2); o.w = f2bf(g3);
  ((ushort4*)(h + (long)r * D_DIM))[t] = o;
}

// ---- out = LayerNorm((engram+pos) + y + b2); y read in-place from out ----
__global__ __launch_bounds__(256) void ln_kernel(const float* __restrict__ eng,
                                                 const float* __restrict__ pos,
                                                 const float* __restrict__ b2,
                                                 const float* __restrict__ gamma,
                                                 const float* __restrict__ beta,
                                                 float* __restrict__ out) {
  __shared__ float red[8];
  int r = blockIdx.x;
  int t = threadIdx.x;
  int bn = r >> 9, w = r & 511;
  int er = bn * 16 + (w >> 5);
  float4 xe = ((const float4*)(eng + er * D_DIM))[t];
  float4 xp = ((const float4*)(pos + w * D_DIM))[t];
  float4 y  = ((const float4*)(out + (long)r * D_DIM))[t];
  float4 bb = ((const float4*)b2)[t];
  float v0 = xe.x + xp.x + y.x + bb.x;
  float v1 = xe.y + xp.y + y.y + bb.y;
  float v2 = xe.z + xp.z + y.z + bb.z;
  float v3 = xe.w + xp.w + y.w + bb.w;
  float s  = v0 + v1 + v2 + v3;
  float sq = v0 * v0 + v1 * v1 + v2 * v2 + v3 * v3;
  int lane = t & 63, wv = t >> 6;
#pragma unroll
  for (int off = 32; off > 0; off >>= 1) {
    s  += __shfl_down(s, off);
    sq += __shfl_down(sq, off);
  }
  if (lane == 0) { red[wv] = s; red[4 + wv] = sq; }
  __syncthreads();
  float S  = red[0] + red[1] + red[2] + red[3];
  float SQ = red[4] + red[5] + red[6] + red[7];
  float mu = S * (1.0f / 1024.0f);
  float var = SQ * (1.0f / 1024.0f) - mu * mu;
  float rs = rsqrtf(var + 1e-5f);
  float4 g = ((const float4*)gamma)[t];
  float4 bt = ((const float4*)beta)[t];
  float4 o;
  o.x = (v0 - mu) * rs * g.x + bt.x;
  o.y = (v1 - mu) * rs * g.y + bt.y;
  o.z = (v2 - mu) * rs * g.z + bt.z;
  o.w = (v3 - mu) * rs * g.w + bt.w;
  ((float4*)(out + (long)r * D_DIM))[t] = o;
}

extern "C" void kernel_launch(void* const* d_in, const int* in_sizes, int n_in,
                              void* d_out, int out_size, void* d_ws, size_t ws_size,
                              hipStream_t stream) {
  const float* eng   = (const float*)d_in[0];
  const float* pos   = (const float*)d_in[1];
  const float* w1    = (const float*)d_in[2];
  const float* b1    = (const float*)d_in[3];
  const float* w2    = (const float*)d_in[4];
  const float* b2    = (const float*)d_in[5];
  const float* gamma = (const float*)d_in[6];
  const float* beta  = (const float*)d_in[7];
  float* out = (float*)d_out;

  char* ws = (char*)d_ws;
  ushort* w1b = (ushort*)(ws);                     // 2 MiB
  ushort* w2b = (ushort*)(ws + (2u << 20));        // 2 MiB
  ushort* a1b = (ushort*)(ws + (4u << 20));        // 3 MiB: 1536x1024 bf16
  float*  xw1 = (float*)(ws + (7u << 20));         // 6 MiB: 1536x1024 f32
  ushort* hb  = (ushort*)(ws + (13u << 20));       // 64 MiB: 32768x1024 bf16

  // 1) casts to bf16
  cast_kernel<<<1024, 256, 0, stream>>>(w1, w1b, 1024 * 1024 / 4);
  cast_kernel<<<1024, 256, 0, stream>>>(w2, w2b, 1024 * 1024 / 4);
  cast_kernel<<<1024, 256, 0, stream>>>(eng, a1b, 1024 * 1024 / 4);
  cast_kernel<<<512, 256, 0, stream>>>(pos, a1b + 1024 * 1024, 512 * 1024 / 4);

  // 2) GEMM1: xw1 = [engrams; pos] @ W1^T   (1536 x 1024 x 1024)
  gemm_bt<<<(A1_ROWS / 128) * (D_DIM / 128), 256, 0, stream>>>(a1b, w1b, xw1,
                                                               A1_ROWS, D_DIM, D_DIM);

  // 3) h = gelu(xw1_e + xw1_p + b1) -> bf16
  gelu_kernel<<<NROWS, 256, 0, stream>>>(xw1, b1, hb);

  // 4) GEMM2: y = h @ W2^T -> fp32 into d_out  (32768 x 1024 x 1024), pipelined
  gemm_bt_256<<<(NROWS / 256) * (D_DIM / 256), 512, 0, stream>>>(hb, w2b, out,
                                                                 NROWS, D_DIM, D_DIM);

  // 5) LayerNorm epilogue (exact fp32 residual recompute), in-place on d_out
  ln_kernel<<<NROWS, 256, 0, stream>>>(eng, pos, b2, gamma, beta, out);
}